// Round 21
// baseline (78.573 us; speedup 1.0000x reference)
//
#include <hip/hip_runtime.h>

#define NE  5
#define V   25
#define NT  300
#define NC  12
#define CO  64
#define WPB 4
#define GX  38          // 38*4 = 152 wave-tasks; 150 t-pairs (2 idle, guarded)

typedef float f4 __attribute__((ext_vector_type(4)));
typedef float f2 __attribute__((ext_vector_type(2)));

// intra-wave LDS ordering: drain this wave's LDS ops + pin compiler ordering.
#define WSYNC() do { asm volatile("s_waitcnt lgkmcnt(0)" ::: "memory"); \
                     __builtin_amdgcn_sched_barrier(0); } while (0)

// select w if bit e of m set, else +0.0
__device__ __forceinline__ float hsel(unsigned m, int e, float w) {
    int s = ((int)(m << (31 - e))) >> 31;
    return __int_as_float(__float_as_int(w) & s);
}

// per-wave scratch float offsets (rows 28 floats = 112B)
#define OW   0      // W[8][28]   rows 0-4 edge w, rows 5-7 feat
#define ODV  224    // DV[5][28]
#define OG   364    // G[5][28]
#define OB   504    // B[3][5][28]   (c,i,u)
#define OFP  924    // FP[15][28]    (k=3i+c, e)
#define OST  1344   // ST rows: swizzled, see STROW
#define SCRF 2364   // floats per wave (16B mult; max STROW+16 = 2364)

// bank-spread ST row address (16B-granular, f4-safe)
#define STROW(r) (OST + (r)*20 + (((r) >> 3) & 7)*4)

__global__ __launch_bounds__(256, 4) void hyper_main(
    const float* __restrict__ x,
    const float* __restrict__ h0, const float* __restrict__ h1,
    const float* __restrict__ h2, const float* __restrict__ h3,
    const float* __restrict__ h4,
    const float* __restrict__ wmlp, const float* __restrict__ bmlp,
    float* __restrict__ out)
{
    __shared__ unsigned RM[125];   // row masks [i*25+v] over e
    __shared__ unsigned CM[125];   // col masks [i*25+e] over u
    __shared__ float    DE[125];   // 1/degree_e
    __shared__ __align__(16) float SCR[WPB][SCRF];

    const int tid  = threadIdx.x;
    const int lane = tid & 63;
    const int wid  = tid >> 6;
    const int b    = blockIdx.y;

    // ---- block init (all branches within 256 threads) ----
    if (tid < 125) {
        int i = tid / 25, v = tid % 25;
        const float* hp = (i==0)?h0:(i==1)?h1:(i==2)?h2:(i==3)?h3:h4;
        unsigned m = 0;
        for (int e = 0; e < V; ++e) if (hp[v*V + e] != 0.f) m |= (1u << e);
        RM[tid] = m;
    } else if (tid < 250) {
        int idx = tid - 125, i = idx / 25, e = idx % 25;
        const float* hp = (i==0)?h0:(i==1)?h1:(i==2)?h2:(i==3)?h3:h4;
        unsigned m = 0; float s = 0.f;
        for (int u = 0; u < V; ++u) {
            float hv = hp[u*V + e];
            s += hv;
            if (hv != 0.f) m |= (1u << u);
        }
        CM[idx] = m;
        DE[idx] = (s != 0.f) ? __fdiv_rn(1.f, s) : 0.f;
    }
    __syncthreads();

    const int pp = blockIdx.x * WPB + wid;   // one t-pair per wave
    const bool wvalid = (pp < NT/2);         // NO early return (barrier below)

    float* S = SCR[wid];

    // ---- prefetch lane constants: item q = r*64+lane over 200 = 8ch x 25e ----
    const float* xb[4]; int lo[4];
    {
        #pragma unroll
        for (int r = 0; r < 4; ++r) {
            int q  = r*64 + lane;
            int qq = (q < 200) ? q : 0;
            int ch = qq / 25, e = qq % 25;
            int xc = (ch < 5) ? (ch + 6 + (ch >= 2 ? 1 : 0)) : (ch - 5);
            lo[r] = OW + ch*28 + e;
            xb[r] = x + (size_t)(b*NC + xc)*NT*V + e;
        }
    }
    const bool act3 = (lane < 8);      // r=3 valid items: q=192..199

    // prologue prefetch: t = 2*pp (idle waves read t=0, value unused)
    float pf0, pf1, pf2, pf3;
    {
        int t0 = wvalid ? 2 * pp : 0;
        pf0 = xb[0][t0*V]; pf1 = xb[1][t0*V];
        pf2 = xb[2][t0*V]; pf3 = xb[3][t0*V];
    }

    for (int tp = 0; tp < 2; ++tp) {

        // ---- commit prefetched W ----
        S[lo[0]] = pf0; S[lo[1]] = pf1; S[lo[2]] = pf2;
        if (act3) S[lo[3]] = pf3;
        WSYNC();

        // ---- issue next-t prefetch (hidden under P1-P3 compute) ----
        if (tp == 0) {
            int tn = wvalid ? (2*pp + 1) : 0;
            pf0 = xb[0][tn*V]; pf1 = xb[1][tn*V];
            pf2 = xb[2][tn*V]; pf3 = xb[3][tn*V];
        }

        // ---- P1: dv (bit-exact numpy fp32 association) + g + B fused ----
        for (int r = 0; r < 2; ++r) {
            int idx = r*64 + lane;
            if (idx < 125) {
                int i = idx / 25, v = idx % 25;
                unsigned m = RM[idx];
                const float* wi = S + OW + i*28;
                f4 w0 = *(const f4*)(wi+0),  w1 = *(const f4*)(wi+4),
                   w2 = *(const f4*)(wi+8),  w3 = *(const f4*)(wi+12),
                   w4 = *(const f4*)(wi+16), w5 = *(const f4*)(wi+20),
                   w6 = *(const f4*)(wi+24);
                float L0 = 0.f, L1 = 0.f, L2 = 0.f, L3 = 0.f;
                L0=__fadd_rn(L0,hsel(m, 0,w0.x)); L1=__fadd_rn(L1,hsel(m, 1,w0.y));
                L2=__fadd_rn(L2,hsel(m, 2,w0.z)); L3=__fadd_rn(L3,hsel(m, 3,w0.w));
                L0=__fadd_rn(L0,hsel(m, 4,w1.x)); L1=__fadd_rn(L1,hsel(m, 5,w1.y));
                L2=__fadd_rn(L2,hsel(m, 6,w1.z)); L3=__fadd_rn(L3,hsel(m, 7,w1.w));
                L0=__fadd_rn(L0,hsel(m, 8,w2.x)); L1=__fadd_rn(L1,hsel(m, 9,w2.y));
                L2=__fadd_rn(L2,hsel(m,10,w2.z)); L3=__fadd_rn(L3,hsel(m,11,w2.w));
                L0=__fadd_rn(L0,hsel(m,12,w3.x)); L1=__fadd_rn(L1,hsel(m,13,w3.y));
                L2=__fadd_rn(L2,hsel(m,14,w3.z)); L3=__fadd_rn(L3,hsel(m,15,w3.w));
                L0=__fadd_rn(L0,hsel(m,16,w4.x)); L1=__fadd_rn(L1,hsel(m,17,w4.y));
                L2=__fadd_rn(L2,hsel(m,18,w4.z)); L3=__fadd_rn(L3,hsel(m,19,w4.w));
                L0=__fadd_rn(L0,hsel(m,20,w5.x)); L1=__fadd_rn(L1,hsel(m,21,w5.y));
                L2=__fadd_rn(L2,hsel(m,22,w5.z)); L3=__fadd_rn(L3,hsel(m,23,w5.w));
                float s = __fadd_rn(__fadd_rn(L0,L1), __fadd_rn(L2,L3));
                s = __fadd_rn(s, hsel(m, 24, w6.x));
                float dvv = (s > 0.f) ? (float)(1.0 / sqrt((double)s)) : 0.f;
                S[ODV + i*28 + v] = dvv;
                S[OG  + i*28 + v] = S[OW + i*28 + v] * DE[idx];
                float f0 = S[OW + 5*28 + v];
                float f1 = S[OW + 6*28 + v];
                float f2v = S[OW + 7*28 + v];
                S[OB + (0*5+i)*28 + v] = dvv * f0;
                S[OB + (1*5+i)*28 + v] = dvv * f1;
                S[OB + (2*5+i)*28 + v] = dvv * f2v;
            }
        }
        WSYNC();

        // ---- P2: FP[3i+c][e] = g[i][e]*sum_u h[u,e]*B[c][i][u] ----
        for (int r = 0; r < 2; ++r) {
            int idx = r*64 + lane;
            if (idx < 125) {
                int i = idx / 25, e = idx % 25;
                unsigned m = CM[idx];
                const float* bp = S + OB + i*28;
                float a0 = 0.f, a1 = 0.f, a2 = 0.f;
                while (m) {
                    int u[5]; bool vl[5];
                    #pragma unroll
                    for (int j = 0; j < 5; ++j) {
                        vl[j] = (m != 0u);
                        u[j]  = __builtin_ctz(m | 0x02000000u); // empty -> 25 (in-row pad)
                        m &= m - 1;
                    }
                    float b0[5], b1[5], b2[5];
                    #pragma unroll
                    for (int j = 0; j < 5; ++j) {
                        b0[j] = bp[u[j]];
                        b1[j] = bp[140 + u[j]];
                        b2[j] = bp[280 + u[j]];
                    }
                    #pragma unroll
                    for (int j = 0; j < 5; ++j) {
                        a0 += vl[j] ? b0[j] : 0.f;
                        a1 += vl[j] ? b1[j] : 0.f;
                        a2 += vl[j] ? b2[j] : 0.f;
                    }
                }
                float gg = S[OG + i*28 + e];
                S[OFP + (i*3+0)*28 + e] = a0 * gg;
                S[OFP + (i*3+1)*28 + e] = a1 * gg;
                S[OFP + (i*3+2)*28 + e] = a2 * gg;
            }
        }
        WSYNC();

        // ---- P3: ST[tp*25+v][3i+c] = dv * sum_e h[v,e]*FP[3i+c][e] ----
        for (int r = 0; r < 2; ++r) {
            int idx = r*64 + lane;
            if (idx < 125) {
                int i = idx / 25, v = idx % 25;
                unsigned m = RM[idx];
                const float* fp = S + OFP + i*3*28;
                float a0 = 0.f, a1 = 0.f, a2 = 0.f;
                while (m) {
                    int u[5]; bool vl[5];
                    #pragma unroll
                    for (int j = 0; j < 5; ++j) {
                        vl[j] = (m != 0u);
                        u[j]  = __builtin_ctz(m | 0x02000000u);
                        m &= m - 1;
                    }
                    float b0[5], b1[5], b2[5];
                    #pragma unroll
                    for (int j = 0; j < 5; ++j) {
                        b0[j] = fp[u[j]];
                        b1[j] = fp[28 + u[j]];
                        b2[j] = fp[56 + u[j]];
                    }
                    #pragma unroll
                    for (int j = 0; j < 5; ++j) {
                        a0 += vl[j] ? b0[j] : 0.f;
                        a1 += vl[j] ? b1[j] : 0.f;
                        a2 += vl[j] ? b2[j] : 0.f;
                    }
                }
                float dd = S[ODV + i*28 + v];
                float* st = S + STROW(tp*25 + v) + i*3;
                st[0] = a0 * dd; st[1] = a1 * dd; st[2] = a2 * dd;
            }
        }
        WSYNC();
    }

    __syncthreads();   // all 4 waves' ST visible block-wide

    // ---- P4: MLP + relu, cross-wave: this wave does o in [16*wid, 16*wid+16)
    // for ALL 4 pairs of the block (200 p's, 2 groups of 100). Each lane packs
    // TWO adjacent p's into f2; the weight is a scalar splat -> v_pk_fma_f32
    // without mov-packing. Per-output order (bias, k0..k14) identical. ----
    if (lane < 50) {
        const int o0 = wid * 16;
        #pragma unroll
        for (int g = 0; g < 2; ++g) {
            int q  = 2*g + (lane >= 25 ? 1 : 0);          // pair-in-block
            int rr = (lane >= 25) ? 2*(lane - 25) : 2*lane; // even row in pair
            const float* SQ = SCR[q];
            const float* ra = SQ + STROW(rr);
            const float* rb = SQ + STROW(rr + 1);
            f4 a0 = *(const f4*)(ra+0), a1 = *(const f4*)(ra+4),
               a2 = *(const f4*)(ra+8), a3 = *(const f4*)(ra+12);
            f4 b0 = *(const f4*)(rb+0), b1 = *(const f4*)(rb+4),
               b2 = *(const f4*)(rb+8), b3 = *(const f4*)(rb+12);
            f2 k0 = {a0.x, b0.x}, k1 = {a0.y, b0.y}, k2 = {a0.z, b0.z},
               k3 = {a0.w, b0.w}, k4 = {a1.x, b1.x}, k5 = {a1.y, b1.y},
               k6 = {a1.z, b1.z}, k7 = {a1.w, b1.w}, k8 = {a2.x, b2.x},
               k9 = {a2.y, b2.y}, k10 = {a2.z, b2.z}, k11 = {a2.w, b2.w},
               k12 = {a3.x, b3.x}, k13 = {a3.y, b3.y}, k14 = {a3.z, b3.z};
            int pg = blockIdx.x*200 + q*50 + rr;
            bool ok = (pg < 7500);
            float* ob = out + (size_t)b*CO*7500 + pg;
            #pragma unroll 4
            for (int oi = 0; oi < 16; ++oi) {
                int o = o0 + oi;
                const float* wm = wmlp + o*15;   // wave-uniform -> scalar loads
                float bb = bmlp[o];
                f2 acc = {bb, bb};
                acc += k0  * wm[ 0]; acc += k1  * wm[ 1];
                acc += k2  * wm[ 2]; acc += k3  * wm[ 3];
                acc += k4  * wm[ 4]; acc += k5  * wm[ 5];
                acc += k6  * wm[ 6]; acc += k7  * wm[ 7];
                acc += k8  * wm[ 8]; acc += k9  * wm[ 9];
                acc += k10 * wm[10]; acc += k11 * wm[11];
                acc += k12 * wm[12]; acc += k13 * wm[13];
                acc += k14 * wm[14];
                f2 res = {fmaxf(acc.x, 0.f), fmaxf(acc.y, 0.f)};
                if (ok) *(f2*)(ob + (size_t)o*7500) = res;
            }
        }
    }
}

extern "C" void kernel_launch(void* const* d_in, const int* in_sizes, int n_in,
                              void* d_out, int out_size, void* d_ws, size_t ws_size,
                              hipStream_t stream) {
    const float* x    = (const float*)d_in[0];
    const float* h0   = (const float*)d_in[1];
    const float* h1   = (const float*)d_in[2];
    const float* h2   = (const float*)d_in[3];
    const float* h3   = (const float*)d_in[4];
    const float* h4   = (const float*)d_in[5];
    const float* wmlp = (const float*)d_in[6];
    const float* bmlp = (const float*)d_in[7];
    float* out = (float*)d_out;

    hyper_main<<<dim3(GX, 64, 1), dim3(256,1,1), 0, stream>>>(
        x, h0, h1, h2, h3, h4, wmlp, bmlp, out);
}

// Round 23
// 78.216 us; speedup vs baseline: 1.0046x; 1.0046x over previous
//
#include <hip/hip_runtime.h>

#define NE  5
#define V   25
#define NT  300
#define NC  12
#define CO  64
#define WPB 4
#define GX  38          // 38*4 = 152 wave-tasks; 150 t-pairs (2 idle, guarded)

typedef float f4 __attribute__((ext_vector_type(4)));
typedef float f2 __attribute__((ext_vector_type(2)));

// intra-wave LDS ordering: drain this wave's LDS ops + pin compiler ordering.
#define WSYNC() do { asm volatile("s_waitcnt lgkmcnt(0)" ::: "memory"); \
                     __builtin_amdgcn_sched_barrier(0); } while (0)

// select w if bit e of m set, else +0.0
__device__ __forceinline__ float hsel(unsigned m, int e, float w) {
    int s = ((int)(m << (31 - e))) >> 31;
    return __int_as_float(__float_as_int(w) & s);
}

// per-wave scratch float offsets (rows 28 floats = 112B)
#define OW   0      // W[8][28]   rows 0-4 edge w, rows 5-7 feat
#define ODV  224    // DV[5][28]
#define OG   364    // G[5][28]
#define OB   504    // B[3][5][28]   (c,i,u)
#define OFP  924    // FP[15][28]    (k=3i+c, e)
#define OSTP 1344   // STP[25][16][2]: row stride 36 (144B, f4-aligned); [v][k][tp]
#define SCRF 2244   // floats per wave (1344 + 25*36 = 2244; 16B mult)

__global__ __launch_bounds__(256, 4) void hyper_main(
    const float* __restrict__ x,
    const float* __restrict__ h0, const float* __restrict__ h1,
    const float* __restrict__ h2, const float* __restrict__ h3,
    const float* __restrict__ h4,
    const float* __restrict__ wmlp, const float* __restrict__ bmlp,
    float* __restrict__ out)
{
    __shared__ unsigned RM[125];   // row masks [i*25+v] over e
    __shared__ unsigned CM[125];   // col masks [i*25+e] over u
    __shared__ float    DE[125];   // 1/degree_e
    __shared__ __align__(16) float SCR[WPB][SCRF];

    const int tid  = threadIdx.x;
    const int lane = tid & 63;
    const int wid  = tid >> 6;
    const int b    = blockIdx.y;

    // ---- block init (all branches within 256 threads) ----
    if (tid < 125) {
        int i = tid / 25, v = tid % 25;
        const float* hp = (i==0)?h0:(i==1)?h1:(i==2)?h2:(i==3)?h3:h4;
        unsigned m = 0;
        for (int e = 0; e < V; ++e) if (hp[v*V + e] != 0.f) m |= (1u << e);
        RM[tid] = m;
    } else if (tid < 250) {
        int idx = tid - 125, i = idx / 25, e = idx % 25;
        const float* hp = (i==0)?h0:(i==1)?h1:(i==2)?h2:(i==3)?h3:h4;
        unsigned m = 0; float s = 0.f;
        for (int u = 0; u < V; ++u) {
            float hv = hp[u*V + e];
            s += hv;
            if (hv != 0.f) m |= (1u << u);
        }
        CM[idx] = m;
        DE[idx] = (s != 0.f) ? __fdiv_rn(1.f, s) : 0.f;
    }
    __syncthreads();

    const int pp = blockIdx.x * WPB + wid;   // one t-pair per wave
    const bool wvalid = (pp < NT/2);         // NO early return (barrier below)

    float* S = SCR[wid];

    // ---- prefetch lane constants: item q = r*64+lane over 200 = 8ch x 25e ----
    const float* xb[4]; int lo[4];
    {
        #pragma unroll
        for (int r = 0; r < 4; ++r) {
            int q  = r*64 + lane;
            int qq = (q < 200) ? q : 0;
            int ch = qq / 25, e = qq % 25;
            int xc = (ch < 5) ? (ch + 6 + (ch >= 2 ? 1 : 0)) : (ch - 5);
            lo[r] = OW + ch*28 + e;
            xb[r] = x + (size_t)(b*NC + xc)*NT*V + e;
        }
    }
    const bool act3 = (lane < 8);      // r=3 valid items: q=192..199

    // prologue prefetch: t = 2*pp (idle waves read t=0, value unused)
    float pf0, pf1, pf2, pf3;
    {
        int t0 = wvalid ? 2 * pp : 0;
        pf0 = xb[0][t0*V]; pf1 = xb[1][t0*V];
        pf2 = xb[2][t0*V]; pf3 = xb[3][t0*V];
    }

    for (int tp = 0; tp < 2; ++tp) {

        // ---- commit prefetched W ----
        S[lo[0]] = pf0; S[lo[1]] = pf1; S[lo[2]] = pf2;
        if (act3) S[lo[3]] = pf3;
        WSYNC();

        // ---- issue next-t prefetch (hidden under P1-P3 compute) ----
        if (tp == 0) {
            int tn = wvalid ? (2*pp + 1) : 0;
            pf0 = xb[0][tn*V]; pf1 = xb[1][tn*V];
            pf2 = xb[2][tn*V]; pf3 = xb[3][tn*V];
        }

        // ---- P1: dv (bit-exact numpy fp32 association) + g + B fused ----
        for (int r = 0; r < 2; ++r) {
            int idx = r*64 + lane;
            if (idx < 125) {
                int i = idx / 25, v = idx % 25;
                unsigned m = RM[idx];
                const float* wi = S + OW + i*28;
                f4 w0 = *(const f4*)(wi+0),  w1 = *(const f4*)(wi+4),
                   w2 = *(const f4*)(wi+8),  w3 = *(const f4*)(wi+12),
                   w4 = *(const f4*)(wi+16), w5 = *(const f4*)(wi+20),
                   w6 = *(const f4*)(wi+24);
                float L0 = 0.f, L1 = 0.f, L2 = 0.f, L3 = 0.f;
                L0=__fadd_rn(L0,hsel(m, 0,w0.x)); L1=__fadd_rn(L1,hsel(m, 1,w0.y));
                L2=__fadd_rn(L2,hsel(m, 2,w0.z)); L3=__fadd_rn(L3,hsel(m, 3,w0.w));
                L0=__fadd_rn(L0,hsel(m, 4,w1.x)); L1=__fadd_rn(L1,hsel(m, 5,w1.y));
                L2=__fadd_rn(L2,hsel(m, 6,w1.z)); L3=__fadd_rn(L3,hsel(m, 7,w1.w));
                L0=__fadd_rn(L0,hsel(m, 8,w2.x)); L1=__fadd_rn(L1,hsel(m, 9,w2.y));
                L2=__fadd_rn(L2,hsel(m,10,w2.z)); L3=__fadd_rn(L3,hsel(m,11,w2.w));
                L0=__fadd_rn(L0,hsel(m,12,w3.x)); L1=__fadd_rn(L1,hsel(m,13,w3.y));
                L2=__fadd_rn(L2,hsel(m,14,w3.z)); L3=__fadd_rn(L3,hsel(m,15,w3.w));
                L0=__fadd_rn(L0,hsel(m,16,w4.x)); L1=__fadd_rn(L1,hsel(m,17,w4.y));
                L2=__fadd_rn(L2,hsel(m,18,w4.z)); L3=__fadd_rn(L3,hsel(m,19,w4.w));
                L0=__fadd_rn(L0,hsel(m,20,w5.x)); L1=__fadd_rn(L1,hsel(m,21,w5.y));
                L2=__fadd_rn(L2,hsel(m,22,w5.z)); L3=__fadd_rn(L3,hsel(m,23,w5.w));
                float s = __fadd_rn(__fadd_rn(L0,L1), __fadd_rn(L2,L3));
                s = __fadd_rn(s, hsel(m, 24, w6.x));
                float dvv = (s > 0.f) ? (float)(1.0 / sqrt((double)s)) : 0.f;
                S[ODV + i*28 + v] = dvv;
                S[OG  + i*28 + v] = S[OW + i*28 + v] * DE[idx];
                float f0 = S[OW + 5*28 + v];
                float f1 = S[OW + 6*28 + v];
                float f2v = S[OW + 7*28 + v];
                S[OB + (0*5+i)*28 + v] = dvv * f0;
                S[OB + (1*5+i)*28 + v] = dvv * f1;
                S[OB + (2*5+i)*28 + v] = dvv * f2v;
            }
        }
        WSYNC();

        // ---- P2: FP[3i+c][e] = g[i][e]*sum_u h[u,e]*B[c][i][u] ----
        for (int r = 0; r < 2; ++r) {
            int idx = r*64 + lane;
            if (idx < 125) {
                int i = idx / 25, e = idx % 25;
                unsigned m = CM[idx];
                const float* bp = S + OB + i*28;
                float a0 = 0.f, a1 = 0.f, a2 = 0.f;
                while (m) {
                    int u[5]; bool vl[5];
                    #pragma unroll
                    for (int j = 0; j < 5; ++j) {
                        vl[j] = (m != 0u);
                        u[j]  = __builtin_ctz(m | 0x02000000u); // empty -> 25 (in-row pad)
                        m &= m - 1;
                    }
                    float b0[5], b1[5], b2[5];
                    #pragma unroll
                    for (int j = 0; j < 5; ++j) {
                        b0[j] = bp[u[j]];
                        b1[j] = bp[140 + u[j]];
                        b2[j] = bp[280 + u[j]];
                    }
                    #pragma unroll
                    for (int j = 0; j < 5; ++j) {
                        a0 += vl[j] ? b0[j] : 0.f;
                        a1 += vl[j] ? b1[j] : 0.f;
                        a2 += vl[j] ? b2[j] : 0.f;
                    }
                }
                float gg = S[OG + i*28 + e];
                S[OFP + (i*3+0)*28 + e] = a0 * gg;
                S[OFP + (i*3+1)*28 + e] = a1 * gg;
                S[OFP + (i*3+2)*28 + e] = a2 * gg;
            }
        }
        WSYNC();

        // ---- P3: STP[v][3i+c][tp] = dv * sum_e h[v,e]*FP[3i+c][e];
        // paired layout [v][k][tp], stride 36 -> P4 f4 reads give
        // {k,k+1}x{tp0,tp1} with no packing. Zero k=15 slots. ----
        for (int r = 0; r < 3; ++r) {
            int idx = r*64 + lane;
            if (idx < 125) {
                int i = idx / 25, v = idx % 25;
                unsigned m = RM[idx];
                const float* fp = S + OFP + i*3*28;
                float a0 = 0.f, a1 = 0.f, a2 = 0.f;
                while (m) {
                    int u[5]; bool vl[5];
                    #pragma unroll
                    for (int j = 0; j < 5; ++j) {
                        vl[j] = (m != 0u);
                        u[j]  = __builtin_ctz(m | 0x02000000u);
                        m &= m - 1;
                    }
                    float b0[5], b1[5], b2[5];
                    #pragma unroll
                    for (int j = 0; j < 5; ++j) {
                        b0[j] = fp[u[j]];
                        b1[j] = fp[28 + u[j]];
                        b2[j] = fp[56 + u[j]];
                    }
                    #pragma unroll
                    for (int j = 0; j < 5; ++j) {
                        a0 += vl[j] ? b0[j] : 0.f;
                        a1 += vl[j] ? b1[j] : 0.f;
                        a2 += vl[j] ? b2[j] : 0.f;
                    }
                }
                float dd = S[ODV + i*28 + v];
                float* stp = S + OSTP + v*36 + tp;
                stp[(3*i+0)*2] = a0 * dd;
                stp[(3*i+1)*2] = a1 * dd;
                stp[(3*i+2)*2] = a2 * dd;
            } else if (idx < 150) {
                S[OSTP + (idx - 125)*36 + 30 + tp] = 0.f;   // k=15 slot
            }
        }
        WSYNC();
    }

    __syncthreads();   // all 4 waves' STP visible block-wide

    // ---- P4: MLP + relu, cross-wave: wave wid does o in [16wid,16wid+16)
    // for all 4 pairs. Lane j = v; acc.x is p=(tp0): q*50+j, acc.y is
    // p=(tp1): q*50+25+j  (R22's bug: these are 25 apart, NOT adjacent —
    // two scalar stores, each a 100B contiguous run per 25-lane group). ----
    if (lane < 50) {
        const int o0 = wid * 16;
        const int j  = (lane >= 25) ? (lane - 25) : lane;
        #pragma unroll
        for (int g = 0; g < 2; ++g) {
            int q = 2*g + (lane >= 25 ? 1 : 0);          // pair-in-block
            bool ok = (blockIdx.x*WPB + q) < NT/2;
            const float* base = SCR[q] + OSTP + j*36;
            f4 c0 = *(const f4*)(base+ 0), c1 = *(const f4*)(base+ 4),
               c2 = *(const f4*)(base+ 8), c3 = *(const f4*)(base+12),
               c4 = *(const f4*)(base+16), c5 = *(const f4*)(base+20),
               c6 = *(const f4*)(base+24), c7 = *(const f4*)(base+28);
            float* ob = out + (size_t)b*CO*7500 + (size_t)blockIdx.x*200 + q*50 + j;
            #pragma unroll 4
            for (int oi = 0; oi < 16; ++oi) {
                int o = o0 + oi;
                const float* wm = wmlp + o*15;   // wave-uniform -> scalar loads
                float bb = bmlp[o];
                f2 acc = {bb, bb};
                acc += (f2){c0.x, c0.y} * wm[ 0];
                acc += (f2){c0.z, c0.w} * wm[ 1];
                acc += (f2){c1.x, c1.y} * wm[ 2];
                acc += (f2){c1.z, c1.w} * wm[ 3];
                acc += (f2){c2.x, c2.y} * wm[ 4];
                acc += (f2){c2.z, c2.w} * wm[ 5];
                acc += (f2){c3.x, c3.y} * wm[ 6];
                acc += (f2){c3.z, c3.w} * wm[ 7];
                acc += (f2){c4.x, c4.y} * wm[ 8];
                acc += (f2){c4.z, c4.w} * wm[ 9];
                acc += (f2){c5.x, c5.y} * wm[10];
                acc += (f2){c5.z, c5.w} * wm[11];
                acc += (f2){c6.x, c6.y} * wm[12];
                acc += (f2){c6.z, c6.w} * wm[13];
                acc += (f2){c7.x, c7.y} * wm[14];
                if (ok) {
                    __builtin_nontemporal_store(fmaxf(acc.x, 0.f),
                                                ob + (size_t)o*7500);
                    __builtin_nontemporal_store(fmaxf(acc.y, 0.f),
                                                ob + (size_t)o*7500 + 25);
                }
            }
        }
    }
}

extern "C" void kernel_launch(void* const* d_in, const int* in_sizes, int n_in,
                              void* d_out, int out_size, void* d_ws, size_t ws_size,
                              hipStream_t stream) {
    const float* x    = (const float*)d_in[0];
    const float* h0   = (const float*)d_in[1];
    const float* h1   = (const float*)d_in[2];
    const float* h2   = (const float*)d_in[3];
    const float* h3   = (const float*)d_in[4];
    const float* h4   = (const float*)d_in[5];
    const float* wmlp = (const float*)d_in[6];
    const float* bmlp = (const float*)d_in[7];
    float* out = (float*)d_out;

    hyper_main<<<dim3(GX, 64, 1), dim3(256,1,1), 0, stream>>>(
        x, h0, h1, h2, h3, h4, wmlp, bmlp, out);
}

// Round 24
// 66.931 us; speedup vs baseline: 1.1739x; 1.1686x over previous
//
#include <hip/hip_runtime.h>

#define NE  5
#define V   25
#define NT  300
#define NC  12
#define CO  64
#define WPB 4
#define GX  38          // 38*4 = 152 wave-tasks; 150 t-pairs (2 idle)

typedef float f4 __attribute__((ext_vector_type(4)));

// intra-wave LDS ordering: drain this wave's LDS ops + pin compiler ordering.
#define WSYNC() do { asm volatile("s_waitcnt lgkmcnt(0)" ::: "memory"); \
                     __builtin_amdgcn_sched_barrier(0); } while (0)

// select w if bit e of m set, else +0.0
__device__ __forceinline__ float hsel(unsigned m, int e, float w) {
    int s = ((int)(m << (31 - e))) >> 31;
    return __int_as_float(__float_as_int(w) & s);
}

// per-wave scratch float offsets (rows 28 floats = 112B)
#define OW   0      // W[8][28]   rows 0-4 edge w, rows 5-7 feat
#define ODV  224    // DV[5][28]
#define OG   364    // G[5][28]
#define OB   504    // B[3][5][28]   (c,i,u)
#define OFP  924    // FP[15][28]    (k=3i+c, e)
#define OST  1344   // ST rows: swizzled, see STROW
#define SCRF 2364   // floats per wave (16B mult; max STROW+16 = 2364)

// bank-spread ST row address (16B-granular, f4-safe)
#define STROW(r) (OST + (r)*20 + (((r) >> 3) & 7)*4)

__global__ __launch_bounds__(256, 4) void hyper_main(
    const float* __restrict__ x,
    const float* __restrict__ h0, const float* __restrict__ h1,
    const float* __restrict__ h2, const float* __restrict__ h3,
    const float* __restrict__ h4,
    const float* __restrict__ wmlp, const float* __restrict__ bmlp,
    float* __restrict__ out)
{
    __shared__ unsigned RM[125];   // row masks [i*25+v] over e
    __shared__ unsigned CM[125];   // col masks [i*25+e] over u
    __shared__ float    DE[125];   // 1/degree_e
    __shared__ __align__(16) float SCR[WPB][SCRF];

    const int tid  = threadIdx.x;
    const int lane = tid & 63;
    const int wid  = tid >> 6;
    const int b    = blockIdx.y;

    // ---- block init (all branches within 256 threads) ----
    if (tid < 125) {
        int i = tid / 25, v = tid % 25;
        const float* hp = (i==0)?h0:(i==1)?h1:(i==2)?h2:(i==3)?h3:h4;
        unsigned m = 0;
        for (int e = 0; e < V; ++e) if (hp[v*V + e] != 0.f) m |= (1u << e);
        RM[tid] = m;
    } else if (tid < 250) {
        int idx = tid - 125, i = idx / 25, e = idx % 25;
        const float* hp = (i==0)?h0:(i==1)?h1:(i==2)?h2:(i==3)?h3:h4;
        unsigned m = 0; float s = 0.f;
        for (int u = 0; u < V; ++u) {
            float hv = hp[u*V + e];
            s += hv;
            if (hv != 0.f) m |= (1u << u);
        }
        CM[idx] = m;
        DE[idx] = (s != 0.f) ? __fdiv_rn(1.f, s) : 0.f;
    }
    __syncthreads();   // only block-wide barrier

    const int pp = blockIdx.x * WPB + wid;   // one t-pair per wave
    if (pp >= NT/2) return;

    float* S = SCR[wid];

    // ---- prefetch lane constants: item q = r*64+lane over 200 = 8ch x 25e ----
    const float* xb[4]; int lo[4];
    {
        #pragma unroll
        for (int r = 0; r < 4; ++r) {
            int q  = r*64 + lane;
            int qq = (q < 200) ? q : 0;
            int ch = qq / 25, e = qq % 25;
            int xc = (ch < 5) ? (ch + 6 + (ch >= 2 ? 1 : 0)) : (ch - 5);
            lo[r] = OW + ch*28 + e;
            xb[r] = x + (size_t)(b*NC + xc)*NT*V + e;
        }
    }
    const bool act3 = (lane < 8);      // r=3 valid items: q=192..199

    // prologue prefetch: t = 2*pp
    float pf0, pf1, pf2, pf3;
    {
        int t0 = 2 * pp;
        pf0 = xb[0][t0*V]; pf1 = xb[1][t0*V];
        pf2 = xb[2][t0*V]; pf3 = xb[3][t0*V];
    }

    for (int tp = 0; tp < 2; ++tp) {

        // ---- commit prefetched W ----
        S[lo[0]] = pf0; S[lo[1]] = pf1; S[lo[2]] = pf2;
        if (act3) S[lo[3]] = pf3;
        WSYNC();

        // ---- issue next-t prefetch (hidden under P1-P3 compute) ----
        if (tp == 0) {
            int tn = 2*pp + 1;
            pf0 = xb[0][tn*V]; pf1 = xb[1][tn*V];
            pf2 = xb[2][tn*V]; pf3 = xb[3][tn*V];
        }

        // ---- P1: dv (bit-exact numpy fp32 association) + g + B fused ----
        for (int r = 0; r < 2; ++r) {
            int idx = r*64 + lane;
            if (idx < 125) {
                int i = idx / 25, v = idx % 25;
                unsigned m = RM[idx];
                const float* wi = S + OW + i*28;
                f4 w0 = *(const f4*)(wi+0),  w1 = *(const f4*)(wi+4),
                   w2 = *(const f4*)(wi+8),  w3 = *(const f4*)(wi+12),
                   w4 = *(const f4*)(wi+16), w5 = *(const f4*)(wi+20),
                   w6 = *(const f4*)(wi+24);
                float L0 = 0.f, L1 = 0.f, L2 = 0.f, L3 = 0.f;
                L0=__fadd_rn(L0,hsel(m, 0,w0.x)); L1=__fadd_rn(L1,hsel(m, 1,w0.y));
                L2=__fadd_rn(L2,hsel(m, 2,w0.z)); L3=__fadd_rn(L3,hsel(m, 3,w0.w));
                L0=__fadd_rn(L0,hsel(m, 4,w1.x)); L1=__fadd_rn(L1,hsel(m, 5,w1.y));
                L2=__fadd_rn(L2,hsel(m, 6,w1.z)); L3=__fadd_rn(L3,hsel(m, 7,w1.w));
                L0=__fadd_rn(L0,hsel(m, 8,w2.x)); L1=__fadd_rn(L1,hsel(m, 9,w2.y));
                L2=__fadd_rn(L2,hsel(m,10,w2.z)); L3=__fadd_rn(L3,hsel(m,11,w2.w));
                L0=__fadd_rn(L0,hsel(m,12,w3.x)); L1=__fadd_rn(L1,hsel(m,13,w3.y));
                L2=__fadd_rn(L2,hsel(m,14,w3.z)); L3=__fadd_rn(L3,hsel(m,15,w3.w));
                L0=__fadd_rn(L0,hsel(m,16,w4.x)); L1=__fadd_rn(L1,hsel(m,17,w4.y));
                L2=__fadd_rn(L2,hsel(m,18,w4.z)); L3=__fadd_rn(L3,hsel(m,19,w4.w));
                L0=__fadd_rn(L0,hsel(m,20,w5.x)); L1=__fadd_rn(L1,hsel(m,21,w5.y));
                L2=__fadd_rn(L2,hsel(m,22,w5.z)); L3=__fadd_rn(L3,hsel(m,23,w5.w));
                float s = __fadd_rn(__fadd_rn(L0,L1), __fadd_rn(L2,L3));
                s = __fadd_rn(s, hsel(m, 24, w6.x));
                float dvv = (s > 0.f) ? (float)(1.0 / sqrt((double)s)) : 0.f;
                S[ODV + i*28 + v] = dvv;
                S[OG  + i*28 + v] = S[OW + i*28 + v] * DE[idx];
                float f0 = S[OW + 5*28 + v];
                float f1 = S[OW + 6*28 + v];
                float f2v = S[OW + 7*28 + v];
                S[OB + (0*5+i)*28 + v] = dvv * f0;
                S[OB + (1*5+i)*28 + v] = dvv * f1;
                S[OB + (2*5+i)*28 + v] = dvv * f2v;
            }
        }
        WSYNC();

        // ---- P2: FP[3i+c][e] = g[i][e]*sum_u h[u,e]*B[c][i][u] ----
        // batched-prefetch bit-loop: 5 indices extracted (pure VALU), 15
        // independent loads issued, one wait, masked adds. Ascending-u order
        // and +0.0 for empty slots -> value-identical to the serial bit-loop.
        for (int r = 0; r < 2; ++r) {
            int idx = r*64 + lane;
            if (idx < 125) {
                int i = idx / 25, e = idx % 25;
                unsigned m = CM[idx];
                const float* bp = S + OB + i*28;
                float a0 = 0.f, a1 = 0.f, a2 = 0.f;
                while (m) {
                    int u[5]; bool vl[5];
                    #pragma unroll
                    for (int j = 0; j < 5; ++j) {
                        vl[j] = (m != 0u);
                        u[j]  = __builtin_ctz(m | 0x02000000u); // empty -> 25 (in-row pad)
                        m &= m - 1;
                    }
                    float b0[5], b1[5], b2[5];
                    #pragma unroll
                    for (int j = 0; j < 5; ++j) {
                        b0[j] = bp[u[j]];
                        b1[j] = bp[140 + u[j]];
                        b2[j] = bp[280 + u[j]];
                    }
                    #pragma unroll
                    for (int j = 0; j < 5; ++j) {
                        a0 += vl[j] ? b0[j] : 0.f;
                        a1 += vl[j] ? b1[j] : 0.f;
                        a2 += vl[j] ? b2[j] : 0.f;
                    }
                }
                float gg = S[OG + i*28 + e];
                S[OFP + (i*3+0)*28 + e] = a0 * gg;
                S[OFP + (i*3+1)*28 + e] = a1 * gg;
                S[OFP + (i*3+2)*28 + e] = a2 * gg;
            }
        }
        WSYNC();

        // ---- P3: ST[tp*25+v][3i+c] = dv * sum_e h[v,e]*FP[3i+c][e] ----
        for (int r = 0; r < 2; ++r) {
            int idx = r*64 + lane;
            if (idx < 125) {
                int i = idx / 25, v = idx % 25;
                unsigned m = RM[idx];
                const float* fp = S + OFP + i*3*28;
                float a0 = 0.f, a1 = 0.f, a2 = 0.f;
                while (m) {
                    int u[5]; bool vl[5];
                    #pragma unroll
                    for (int j = 0; j < 5; ++j) {
                        vl[j] = (m != 0u);
                        u[j]  = __builtin_ctz(m | 0x02000000u);
                        m &= m - 1;
                    }
                    float b0[5], b1[5], b2[5];
                    #pragma unroll
                    for (int j = 0; j < 5; ++j) {
                        b0[j] = fp[u[j]];
                        b1[j] = fp[28 + u[j]];
                        b2[j] = fp[56 + u[j]];
                    }
                    #pragma unroll
                    for (int j = 0; j < 5; ++j) {
                        a0 += vl[j] ? b0[j] : 0.f;
                        a1 += vl[j] ? b1[j] : 0.f;
                        a2 += vl[j] ? b2[j] : 0.f;
                    }
                }
                float dd = S[ODV + i*28 + v];
                float* st = S + STROW(tp*25 + v) + i*3;
                st[0] = a0 * dd; st[1] = a1 * dd; st[2] = a2 * dd;
            }
        }
        WSYNC();
    }

    // ---- P4: MLP + relu. Scalar per-o chain, swizzled ST rows ----
    if (lane < 50) {
        const float* st = S + STROW(lane);
        f4 s0 = *(const f4*)(st+0), s1 = *(const f4*)(st+4),
           s2 = *(const f4*)(st+8), s3 = *(const f4*)(st+12);
        s3.w = 0.f;
        float* ob = out + (size_t)b*CO*7500 + (size_t)pp*50 + lane;
        #pragma unroll 8
        for (int o = 0; o < CO; ++o) {
            const float* wm = wmlp + o*15;   // wave-uniform -> scalar loads
            float a = bmlp[o];
            a = fmaf(wm[ 0], s0.x, a); a = fmaf(wm[ 1], s0.y, a);
            a = fmaf(wm[ 2], s0.z, a); a = fmaf(wm[ 3], s0.w, a);
            a = fmaf(wm[ 4], s1.x, a); a = fmaf(wm[ 5], s1.y, a);
            a = fmaf(wm[ 6], s1.z, a); a = fmaf(wm[ 7], s1.w, a);
            a = fmaf(wm[ 8], s2.x, a); a = fmaf(wm[ 9], s2.y, a);
            a = fmaf(wm[10], s2.z, a); a = fmaf(wm[11], s2.w, a);
            a = fmaf(wm[12], s3.x, a); a = fmaf(wm[13], s3.y, a);
            a = fmaf(wm[14], s3.z, a);
            __builtin_nontemporal_store(fmaxf(a, 0.f), ob + (size_t)o*7500);
        }
    }
}

extern "C" void kernel_launch(void* const* d_in, const int* in_sizes, int n_in,
                              void* d_out, int out_size, void* d_ws, size_t ws_size,
                              hipStream_t stream) {
    const float* x    = (const float*)d_in[0];
    const float* h0   = (const float*)d_in[1];
    const float* h1   = (const float*)d_in[2];
    const float* h2   = (const float*)d_in[3];
    const float* h3   = (const float*)d_in[4];
    const float* h4   = (const float*)d_in[5];
    const float* wmlp = (const float*)d_in[6];
    const float* bmlp = (const float*)d_in[7];
    float* out = (float*)d_out;

    hyper_main<<<dim3(GX, 64, 1), dim3(256,1,1), 0, stream>>>(
        x, h0, h1, h2, h3, h4, wmlp, bmlp, out);
}